// Round 9
// baseline (619.262 us; speedup 1.0000x reference)
//
#include <hip/hip_runtime.h>
#include <hip/hip_bf16.h>

// Problem constants
#define NPIX   16384      // 128*128
#define NRROWS 2048       // r rows
#define NLROWS 5120       // l rows
#define NVROWS 4096       // v rows (= GEMM M)
#define GK     5120       // original K (fallback path)
#define KF     2048       // folded GEMM K  (lgn_idx only indexes [0,2048))
#define KEXTRA 3072       // duplicated LGN rows folded into conn
#define KTILES 32         // mask granularity: 64-slot tiles
#define NCB    (NPIX / 256) // 64 col-blocks
#define TAU    1e-4f      // A-side tile drop threshold; err <= TAU*sum|r| ~ 5e-5

using f32x4    = __attribute__((ext_vector_type(4))) float;
using bf16x8   = __attribute__((ext_vector_type(8))) __bf16;
using ushortx8 = __attribute__((ext_vector_type(8))) unsigned short;

// fp32 -> bf16 round-to-nearest-even (no NaN inputs in this problem)
__device__ __forceinline__ unsigned short f2b(float f) {
    union { float f; unsigned u; } v; v.f = f;
    unsigned r = (v.u + 0x7FFFu + ((v.u >> 16) & 1u)) >> 16;
    return (unsigned short)r;
}

#define GLOAD_LDS16(gsrc, ldst)                                                        \
    __builtin_amdgcn_global_load_lds(                                                  \
        (const __attribute__((address_space(1))) void*)(gsrc),                         \
        (__attribute__((address_space(3))) void*)(ldst), 16, 0, 0)

// ---------------- prep: analytic y-sort + inverse CSR + amask zero ----------------
// RGC lattice: pos=[i,j], y = sqrt(3)*(i-j)*L (+noise 0.155L, sub-band). key=(i-j)+31
// sorts by y WITHOUT reading act. A wrong key only degrades sparsity (speed), never
// correctness — the skip masks are measured from the data.
__global__ __launch_bounds__(256) void prep_kernel(const int* __restrict__ lgn_idx,
                                                   int* __restrict__ order,
                                                   int* __restrict__ inv_off,
                                                   int* __restrict__ inv_j,
                                                   unsigned int* __restrict__ amask) {
    __shared__ int bins[64];
    __shared__ int cnt[KF];             // 8 KB
    __shared__ int part[256];
    __shared__ int spart[257];
    const int t = threadIdx.x;
    if (t < 64) bins[t] = 0;
    if (t < 16) amask[t] = 0u;
    __syncthreads();
    for (int k = t; k < KF; k += 256) {
        int base = k & 1023;
        int key = ((base >> 5) - (base & 31)) + 31;   // 0..62
        atomicAdd(&bins[key], 1);
    }
    __syncthreads();
    if (t == 0) {
        int run = 0;
        for (int b = 0; b < 63; ++b) { int c = bins[b]; bins[b] = run; run += c; }
    }
    __syncthreads();
    for (int k = t; k < KF; k += 256) {
        int base = k & 1023;
        int key = ((base >> 5) - (base & 31)) + 31;
        int slot = atomicAdd(&bins[key], 1);
        order[slot] = k;
    }
    // ---- inverse CSR of lgn_idx ----
    for (int i = t; i < KF; i += 256) cnt[i] = 0;
    __syncthreads();
    for (int j = t; j < KEXTRA; j += 256) atomicAdd(&cnt[lgn_idx[j]], 1);
    __syncthreads();
    const int base8 = t * 8;
    int local[8];
    {
        int s = 0;
        #pragma unroll
        for (int i = 0; i < 8; ++i) { local[i] = s; s += cnt[base8 + i]; }
        part[t] = s;
    }
    __syncthreads();
    if (t == 0) {
        int run = 0;
        for (int i = 0; i < 256; ++i) { spart[i] = run; run += part[i]; }
        spart[256] = run;
    }
    __syncthreads();
    #pragma unroll
    for (int i = 0; i < 8; ++i) {
        int o = spart[t] + local[i];
        inv_off[base8 + i] = o;
        cnt[base8 + i] = o;             // reuse as scatter cursor
    }
    if (t == 0) inv_off[KF] = spart[256];
    __syncthreads();
    for (int j = t; j < KEXTRA; j += 256) {
        int s = atomicAdd(&cnt[lgn_idx[j]], 1);
        inv_j[s] = j;
    }
}

// ---------------- combo: lgn stage (by<32) || conn fold (by>=32) ----------------
__global__ __launch_bounds__(256) void combo_kernel(const float* __restrict__ x,
                                                    const float* __restrict__ act_on,
                                                    const float* __restrict__ act_off,
                                                    const float* __restrict__ conn,
                                                    const int* __restrict__ lgn_idx,
                                                    const int* __restrict__ order,
                                                    const int* __restrict__ inv_off,
                                                    const int* __restrict__ inv_j,
                                                    float* __restrict__ r,
                                                    float* __restrict__ l,
                                                    unsigned short* __restrict__ rbt,
                                                    unsigned char* __restrict__ nzb,
                                                    unsigned short* __restrict__ Ab,
                                                    unsigned int* __restrict__ amask) {
    __shared__ unsigned short tile[64][66];
    __shared__ float acc[KF];
    __shared__ int nzf;
    __shared__ unsigned int rmask;
    const int t = threadIdx.x;

    if (blockIdx.y < KTILES) {
        // ======== lgn path: r, l (incl. dups via inverse CSR), rbt, nzb ========
        const int k0 = blockIdx.y * 64;     // slot base (sorted)
        const int n0 = blockIdx.x * 64;     // pixel tile base
        if (t == 0) nzf = 0;
        __syncthreads();
        #pragma unroll
        for (int p = 0; p < 4; ++p) {
            int row  = p * 16 + (t >> 4);
            int kk   = k0 + row;            // slot
            int lrow = order[kk];           // original row id (< 2048)
            int c4   = t & 15;
            int px   = n0 + c4 * 4;
            float4 xv = *reinterpret_cast<const float4*>(&x[px]);
            float4 d;
            if (lrow < 1024) {
                float4 a = *reinterpret_cast<const float4*>(&act_on[(size_t)lrow * NPIX + px]);
                d.x = xv.x * a.x; d.y = xv.y * a.y; d.z = xv.z * a.z; d.w = xv.w * a.w;
            } else {
                float4 a = *reinterpret_cast<const float4*>(&act_off[(size_t)(lrow - 1024) * NPIX + px]);
                d.x = (1.f - xv.x) * a.x; d.y = (1.f - xv.y) * a.y;
                d.z = (1.f - xv.z) * a.z; d.w = (1.f - xv.w) * a.w;
            }
            *reinterpret_cast<float4*>(&l[(size_t)lrow * NPIX + px]) = d;
            *reinterpret_cast<float4*>(&r[(size_t)lrow * NPIX + px]) = d;
            int e0 = inv_off[lrow], e1 = inv_off[lrow + 1];
            for (int e = e0; e < e1; ++e)
                *reinterpret_cast<float4*>(&l[(size_t)(NRROWS + inv_j[e]) * NPIX + px]) = d;
            tile[row][c4 * 4 + 0] = f2b(d.x);
            tile[row][c4 * 4 + 1] = f2b(d.y);
            tile[row][c4 * 4 + 2] = f2b(d.z);
            tile[row][c4 * 4 + 3] = f2b(d.w);
            if (d.x != 0.f || d.y != 0.f || d.z != 0.f || d.w != 0.f) nzf = 1; // benign race
        }
        __syncthreads();
        #pragma unroll
        for (int p = 0; p < 4; ++p) {
            int nn = p * 16 + (t >> 4);     // output row (= pixel)
            int k4 = t & 15;
            ushort4 s;
            s.x = tile[k4 * 4 + 0][nn];
            s.y = tile[k4 * 4 + 1][nn];
            s.z = tile[k4 * 4 + 2][nn];
            s.w = tile[k4 * 4 + 3][nn];
            *reinterpret_cast<ushort4*>(&rbt[(size_t)(n0 + nn) * KF + k0 + k4 * 4]) = s;
        }
        if (t == 0) nzb[blockIdx.y * 256 + blockIdx.x] = (unsigned char)nzf;
    } else {
        // ======== fold path: Abf[row][s] = f2b(folded[order[s]]), amask ========
        const int row = (blockIdx.y - KTILES) * 256 + blockIdx.x;   // 0..4095
        if (t == 0) rmask = 0u;
        const float* crow = conn + (size_t)row * GK;
        #pragma unroll
        for (int i = 0; i < KF / 256; ++i)
            acc[t + 256 * i] = crow[t + 256 * i];
        __syncthreads();
        #pragma unroll
        for (int j = 0; j < KEXTRA / 256; ++j) {
            int jj = t + 256 * j;
            float v = crow[KF + jj];
            atomicAdd(&acc[lgn_idx[jj]], v);
        }
        __syncthreads();
        unsigned int local = 0u;
        #pragma unroll
        for (int i = 0; i < KF / 256; ++i) {
            int c = t + 256 * i;
            float v = acc[order[c]];
            Ab[(size_t)row * KF + c] = f2b(v);
            if (fabsf(v) >= TAU) local |= 1u << (c >> 6);
        }
        atomicOr(&rmask, local);
        __syncthreads();
        if (t == 0) atomicOr(&amask[row >> 8], rmask);
    }
}

// ---------------- Stage 3: v = conn_folded @ r — doubly block-sparse, BK=32 --------
// LDS 64KB + __launch_bounds__(512,4) -> 2 blocks/CU: one block's C-write/barrier
// stalls overlap the other's MFMA phases. Each 64-slot mask tile expands to two
// 32-k steps in order -> bit-identical accumulation to the BK=64 version.
// 2-barrier schedule per 32-k step: ph0 stages A(next) (2 issues), ph1 stages
// B(next) (2); end-ph1 vmcnt(4) publishes B-hi(cur); end-ph3 vmcnt(1) publishes
// A+B-lo(next). At 64B row stride the lane->bank map is uniform (8 words/bank
// minimum) with NO swizzle: position = (row&1)*64 + kg*16 covers all 8 slots x8.
__global__ __launch_bounds__(512, 4) void gemm8_kernel(const unsigned short* __restrict__ Ab, // conn_folded bf16 [4096][2048]
                                                       const unsigned short* __restrict__ Bb, // rbt [16384][2048]
                                                       const unsigned char* __restrict__ nzb, // [32][256]
                                                       const unsigned int* __restrict__ amask, // [16]
                                                       float* __restrict__ C) {               // v [4096][16384]
    __shared__ unsigned short lds[2][2][256][32];   // 64KB: [buf][A=0/B=1][row][k]
    __shared__ unsigned int s_ok[KTILES];
    __shared__ int s_klist[2 * KTILES];
    __shared__ int s_cnt;

    const int tid  = threadIdx.x;
    const int lane = tid & 63;
    const int wid  = tid >> 6;
    const int wm   = wid >> 2;
    const int wn   = wid & 3;

    // XCD-aware bijective swizzle: 1024 wg, 8 XCDs, m-fast within XCD chunk.
    int bid = blockIdx.x;
    int swz = (bid & 7) * 128 + (bid >> 3);
    int mb  = swz & 15;
    int nb  = swz >> 4;
    const int row0 = mb * 256;
    const int col0 = nb * 256;

    if (tid < KTILES)
        s_ok[tid] = reinterpret_cast<const unsigned int*>(nzb)[tid * 64 + nb];
    __syncthreads();
    if (tid == 0) {
        unsigned int am = amask[mb];
        int c = 0;
        for (int kt = 0; kt < KTILES; ++kt)
            if (s_ok[kt] && ((am >> kt) & 1u)) { s_klist[c++] = kt * 2; s_klist[c++] = kt * 2 + 1; }
        s_cnt = c;
    }
    __syncthreads();
    const int cnt = s_cnt;

    const int strow = tid >> 2;          // 0..127 rows within an issue half
    const int kc    = lane & 3;          // 16B chunk (8 k) — linear, no swizzle

#define STAGE_A(buf, half, ks)                                                          \
    GLOAD_LDS16(&Ab[(size_t)(row0 + (half) * 128 + strow) * KF + (ks) * 32 + kc * 8],   \
                &lds[buf][0][(half) * 128 + strow][kc * 8])
#define STAGE_B(buf, half, ks)                                                          \
    GLOAD_LDS16(&Bb[(size_t)(col0 + (half) * 128 + strow) * KF + (ks) * 32 + kc * 8],   \
                &lds[buf][1][(half) * 128 + strow][kc * 8])
#define FRAG(buf, op, row)                                                              \
    __builtin_bit_cast(bf16x8, *reinterpret_cast<const ushortx8*>(                      \
        &lds[buf][op][row][kg * 8]))

    f32x4 acc[2][2][4][2] = {};      // [qm][qn][m][n]
    const int fr = lane & 15;
    const int kg = lane >> 4;        // k-chunk of 8 within the 32

    bf16x8 af[2][4];                 // both A halves in registers
    bf16x8 b[2];                     // current B half

    if (cnt > 0) {
        const int ks0 = s_klist[0];
        STAGE_A(0, 0, ks0); STAGE_A(0, 1, ks0);
        STAGE_B(0, 0, ks0); STAGE_B(0, 1, ks0);
        asm volatile("s_waitcnt vmcnt(1)" ::: "memory");   // A full + B-lo landed
        __builtin_amdgcn_s_barrier();

        for (int t = 0; t < cnt - 1; ++t) {
            const int cur = t & 1;
            const int nxt = cur ^ 1;
            const int ksn = s_klist[t + 1];

            // ======== ph0: Q(0,0) — consume A-lo, B-lo; stage A(next) ========
            #pragma unroll
            for (int m = 0; m < 4; ++m)
                af[0][m] = FRAG(cur, 0, wm * 64 + m * 16 + fr);
            #pragma unroll
            for (int n = 0; n < 2; ++n)
                b[n] = FRAG(cur, 1, wn * 32 + n * 16 + fr);
            STAGE_A(nxt, 0, ksn); STAGE_A(nxt, 1, ksn);
            __builtin_amdgcn_s_setprio(1);
            #pragma unroll
            for (int m = 0; m < 4; ++m)
                #pragma unroll
                for (int n = 0; n < 2; ++n)
                    acc[0][0][m][n] = __builtin_amdgcn_mfma_f32_16x16x32_bf16(af[0][m], b[n], acc[0][0][m][n], 0, 0, 0);
            __builtin_amdgcn_s_setprio(0);

            // ======== ph1: Q(1,0) — consume A-hi; stage B(next) ========
            #pragma unroll
            for (int m = 0; m < 4; ++m)
                af[1][m] = FRAG(cur, 0, 128 + wm * 64 + m * 16 + fr);
            STAGE_B(nxt, 0, ksn); STAGE_B(nxt, 1, ksn);
            __builtin_amdgcn_s_setprio(1);
            #pragma unroll
            for (int m = 0; m < 4; ++m)
                #pragma unroll
                for (int n = 0; n < 2; ++n)
                    acc[1][0][m][n] = __builtin_amdgcn_mfma_f32_16x16x32_bf16(af[1][m], b[n], acc[1][0][m][n], 0, 0, 0);
            __builtin_amdgcn_s_setprio(0);
            asm volatile("s_waitcnt vmcnt(4)" ::: "memory");         // B-hi(cur) landed
            __builtin_amdgcn_s_barrier();                            // publish B-hi(cur)

            // ======== ph2: Q(1,1) — consume B-hi ========
            #pragma unroll
            for (int n = 0; n < 2; ++n)
                b[n] = FRAG(cur, 1, 128 + wn * 32 + n * 16 + fr);
            __builtin_amdgcn_s_setprio(1);
            #pragma unroll
            for (int m = 0; m < 4; ++m)
                #pragma unroll
                for (int n = 0; n < 2; ++n)
                    acc[1][1][m][n] = __builtin_amdgcn_mfma_f32_16x16x32_bf16(af[1][m], b[n], acc[1][1][m][n], 0, 0, 0);
            __builtin_amdgcn_s_setprio(0);

            // ======== ph3: Q(0,1) — pure-reg ========
            __builtin_amdgcn_s_setprio(1);
            #pragma unroll
            for (int m = 0; m < 4; ++m)
                #pragma unroll
                for (int n = 0; n < 2; ++n)
                    acc[0][1][m][n] = __builtin_amdgcn_mfma_f32_16x16x32_bf16(af[0][m], b[n], acc[0][1][m][n], 0, 0, 0);
            __builtin_amdgcn_s_setprio(0);
            asm volatile("s_waitcnt vmcnt(1)" ::: "memory");         // A(next)+B-lo(next) landed
            __builtin_amdgcn_s_barrier();                            // publish next step inputs
        }

        // ======== epilogue: last 32-k step ========
        {
            const int cur = (cnt - 1) & 1;
            #pragma unroll
            for (int m = 0; m < 4; ++m)
                af[0][m] = FRAG(cur, 0, wm * 64 + m * 16 + fr);
            #pragma unroll
            for (int n = 0; n < 2; ++n)
                b[n] = FRAG(cur, 1, wn * 32 + n * 16 + fr);
            #pragma unroll
            for (int m = 0; m < 4; ++m)
                #pragma unroll
                for (int n = 0; n < 2; ++n)
                    acc[0][0][m][n] = __builtin_amdgcn_mfma_f32_16x16x32_bf16(af[0][m], b[n], acc[0][0][m][n], 0, 0, 0);
            #pragma unroll
            for (int m = 0; m < 4; ++m)
                af[1][m] = FRAG(cur, 0, 128 + wm * 64 + m * 16 + fr);
            #pragma unroll
            for (int m = 0; m < 4; ++m)
                #pragma unroll
                for (int n = 0; n < 2; ++n)
                    acc[1][0][m][n] = __builtin_amdgcn_mfma_f32_16x16x32_bf16(af[1][m], b[n], acc[1][0][m][n], 0, 0, 0);
            asm volatile("s_waitcnt vmcnt(0)" ::: "memory");         // B-hi(last) landed
            __builtin_amdgcn_s_barrier();
            #pragma unroll
            for (int n = 0; n < 2; ++n)
                b[n] = FRAG(cur, 1, 128 + wn * 32 + n * 16 + fr);
            #pragma unroll
            for (int m = 0; m < 4; ++m)
                #pragma unroll
                for (int n = 0; n < 2; ++n) {
                    acc[1][1][m][n] = __builtin_amdgcn_mfma_f32_16x16x32_bf16(af[1][m], b[n], acc[1][1][m][n], 0, 0, 0);
                    acc[0][1][m][n] = __builtin_amdgcn_mfma_f32_16x16x32_bf16(af[0][m], b[n], acc[0][1][m][n], 0, 0, 0);
                }
        }
    }

    // C write: C/D layout col=lane&15, row=(lane>>4)*4+j
    #pragma unroll
    for (int qm = 0; qm < 2; ++qm)
        #pragma unroll
        for (int qn = 0; qn < 2; ++qn)
            #pragma unroll
            for (int m = 0; m < 4; ++m)
                #pragma unroll
                for (int n = 0; n < 2; ++n) {
                    int rr = row0 + qm * 128 + wm * 64 + m * 16 + kg * 4;
                    int cc = col0 + qn * 128 + wn * 32 + n * 16 + fr;
                    #pragma unroll
                    for (int j = 0; j < 4; ++j)
                        C[(size_t)(rr + j) * NPIX + cc] = acc[qm][qn][m][n][j];
                }
#undef STAGE_A
#undef STAGE_B
#undef FRAG
}

// ---------------- Fallback path (workspace too small) ----------------
__global__ __launch_bounds__(256) void rgc_kernel(const float* __restrict__ x,
                                                  const float* __restrict__ act_on,
                                                  const float* __restrict__ act_off,
                                                  float* __restrict__ r) {
    unsigned f = blockIdx.x * 256u + threadIdx.x;     // float4 index
    unsigned n  = f >> 12;
    unsigned p4 = f & 4095u;
    float4 xv = reinterpret_cast<const float4*>(x)[p4];
    float4 a, o;
    if (n < 1024u) {
        a = reinterpret_cast<const float4*>(act_on)[(size_t)n * 4096u + p4];
        o.x = xv.x * a.x; o.y = xv.y * a.y; o.z = xv.z * a.z; o.w = xv.w * a.w;
    } else {
        a = reinterpret_cast<const float4*>(act_off)[(size_t)(n - 1024u) * 4096u + p4];
        o.x = (1.f - xv.x) * a.x; o.y = (1.f - xv.y) * a.y;
        o.z = (1.f - xv.z) * a.z; o.w = (1.f - xv.w) * a.w;
    }
    reinterpret_cast<float4*>(r)[f] = o;
}

__global__ __launch_bounds__(256) void lgn_kernel(const float* __restrict__ r,
                                                  const int* __restrict__ lgn_idx,
                                                  float* __restrict__ l) {
    unsigned f = blockIdx.x * 256u + threadIdx.x;
    unsigned k  = f >> 12;
    unsigned p4 = f & 4095u;
    unsigned src = (k < 2048u) ? k : (unsigned)lgn_idx[k - 2048u];
    reinterpret_cast<float4*>(l)[f] =
        reinterpret_cast<const float4*>(r)[(size_t)src * 4096u + p4];
}

__global__ __launch_bounds__(256) void gemm_fallback_kernel(const float* __restrict__ A,
                                                            const float* __restrict__ B,
                                                            float* __restrict__ C) {
    const int tid  = threadIdx.x;
    const int lane = tid & 63;
    const int wid  = tid >> 6;
    const int wr   = wid >> 1;
    const int wc   = wid & 1;
    const int row0 = blockIdx.y * 128;
    const int col0 = blockIdx.x * 128;

    __shared__ unsigned short As[4][128][8];
    __shared__ unsigned short Bs[4][128][8];

    f32x4 acc[4][4] = {};

    for (int k0 = 0; k0 < GK; k0 += 32) {
        #pragma unroll
        for (int i = 0; i < 4; ++i) {
            int f  = tid + 256 * i;
            int rr = f >> 3;
            int c4 = f & 7;
            float4 d = *reinterpret_cast<const float4*>(
                &A[(size_t)(row0 + rr) * GK + k0 + c4 * 4]);
            ushort4 s;
            s.x = f2b(d.x); s.y = f2b(d.y); s.z = f2b(d.z); s.w = f2b(d.w);
            *reinterpret_cast<ushort4*>(&As[c4 >> 1][rr][(c4 & 1) * 4]) = s;
        }
        #pragma unroll
        for (int i = 0; i < 4; ++i) {
            int f  = tid + 256 * i;
            int kk = f >> 5;
            int c4 = f & 31;
            float4 d = *reinterpret_cast<const float4*>(
                &B[(size_t)(k0 + kk) * NPIX + col0 + c4 * 4]);
            int g = kk >> 3, j = kk & 7;
            Bs[g][c4 * 4 + 0][j] = f2b(d.x);
            Bs[g][c4 * 4 + 1][j] = f2b(d.y);
            Bs[g][c4 * 4 + 2][j] = f2b(d.z);
            Bs[g][c4 * 4 + 3][j] = f2b(d.w);
        }
        __syncthreads();

        const int fr = lane & 15;
        const int kg = lane >> 4;
        bf16x8 af[4], bfr[4];
        #pragma unroll
        for (int m = 0; m < 4; ++m)
            af[m] = __builtin_bit_cast(bf16x8,
                *reinterpret_cast<const ushortx8*>(&As[kg][wr * 64 + m * 16 + fr][0]));
        #pragma unroll
        for (int n = 0; n < 4; ++n)
            bfr[n] = __builtin_bit_cast(bf16x8,
                *reinterpret_cast<const ushortx8*>(&Bs[kg][wc * 64 + n * 16 + fr][0]));
        #pragma unroll
        for (int m = 0; m < 4; ++m)
            #pragma unroll
            for (int n = 0; n < 4; ++n)
                acc[m][n] = __builtin_amdgcn_mfma_f32_16x16x32_bf16(af[m], bfr[n], acc[m][n], 0, 0, 0);
        __syncthreads();
    }

    #pragma unroll
    for (int m = 0; m < 4; ++m) {
        #pragma unroll
        for (int n = 0; n < 4; ++n) {
            int rr = row0 + wr * 64 + m * 16 + ((lane >> 4) << 2);
            int cc = col0 + wc * 64 + n * 16 + (lane & 15);
            #pragma unroll
            for (int j = 0; j < 4; ++j)
                C[(size_t)(rr + j) * NPIX + cc] = acc[m][n][j];
        }
    }
}

extern "C" void kernel_launch(void* const* d_in, const int* in_sizes, int n_in,
                              void* d_out, int out_size, void* d_ws, size_t ws_size,
                              hipStream_t stream) {
    const float* x       = (const float*)d_in[0];
    const float* act_on  = (const float*)d_in[1];
    const float* act_off = (const float*)d_in[2];
    const float* conn    = (const float*)d_in[3];
    const int*   lgn_idx = (const int*)d_in[4];

    float* out = (float*)d_out;
    float* r = out;                                    // [2048][16384]
    float* l = out + (size_t)NRROWS * NPIX;            // [5120][16384]
    float* v = out + (size_t)(NRROWS + NLROWS) * NPIX; // [4096][16384]

    const size_t rbt_bytes  = (size_t)NPIX * KF * sizeof(unsigned short);   // 67.1 MB
    const size_t conn_bytes = (size_t)NVROWS * KF * sizeof(unsigned short); // 16.8 MB
    const size_t small_bytes = (KF + (KF + 1) + KEXTRA + 16 + 64) * sizeof(int)
                             + KTILES * 256;

    if (ws_size >= rbt_bytes + conn_bytes + small_bytes) {
        char* wsp = (char*)d_ws;
        unsigned short* rbt    = (unsigned short*)wsp;                wsp += rbt_bytes;
        unsigned short* connb  = (unsigned short*)wsp;                wsp += conn_bytes;
        int*            order  = (int*)wsp;                           wsp += KF * sizeof(int);
        int*            invoff = (int*)wsp;                           wsp += (KF + 1) * sizeof(int);
        int*            invj   = (int*)wsp;                           wsp += KEXTRA * sizeof(int);
        unsigned char*  nzb    = (unsigned char*)wsp;                 wsp += KTILES * 256;
        unsigned int*   amask  = (unsigned int*)wsp;

        // analytic y-sort + inverse CSR + amask zero (one tiny kernel, no act read)
        prep_kernel<<<1, 256, 0, stream>>>(lgn_idx, order, invoff, invj, amask);
        // combo: lgn stage (r,l,rbt,nzb) || conn fold (connb, amask) — overlapped
        dim3 tg(NPIX / 64, KTILES + NVROWS / 256);
        combo_kernel<<<tg, 256, 0, stream>>>(x, act_on, act_off, conn, lgn_idx, order,
                                             invoff, invj, r, l, rbt, nzb, connb, amask);
        // Stage 3: doubly block-sparse v = conn_folded @ r (BK=32, 2 blocks/CU;
        // per-block bmask from nzb — bmask_build kernel removed)
        gemm8_kernel<<<(NVROWS / 256) * (NPIX / 256), 512, 0, stream>>>(connb, rbt, nzb, amask, v);
    } else {
        rgc_kernel<<<(NRROWS * (NPIX / 4)) / 256, 256, 0, stream>>>(x, act_on, act_off, r);
        lgn_kernel<<<(NLROWS * (NPIX / 4)) / 256, 256, 0, stream>>>(r, lgn_idx, l);
        dim3 grid(NPIX / 128, NVROWS / 128);
        gemm_fallback_kernel<<<grid, 256, 0, stream>>>(conn, l, v);
    }
}

// Round 10
// 308.948 us; speedup vs baseline: 2.0044x; 2.0044x over previous
//
#include <hip/hip_runtime.h>
#include <hip/hip_bf16.h>

// Problem constants
#define NPIX   16384      // 128*128
#define NRROWS 2048       // r rows
#define NLROWS 5120       // l rows
#define NVROWS 4096       // v rows (= GEMM M)
#define GK     5120       // original K (fallback path)
#define KF     2048       // folded GEMM K  (lgn_idx only indexes [0,2048))
#define KEXTRA 3072       // duplicated LGN rows folded into conn
#define BK8    64         // GEMM K-step
#define KTILES (KF / BK8) // 32 k-tiles
#define NCB    (NPIX / 256) // 64 col-blocks
#define TAU    1e-4f      // A-side tile drop threshold; err <= TAU*sum|r| ~ 5e-5

using f32x4    = __attribute__((ext_vector_type(4))) float;
using bf16x8   = __attribute__((ext_vector_type(8))) __bf16;
using ushortx8 = __attribute__((ext_vector_type(8))) unsigned short;

// fp32 -> bf16 round-to-nearest-even (no NaN inputs in this problem)
__device__ __forceinline__ unsigned short f2b(float f) {
    union { float f; unsigned u; } v; v.f = f;
    unsigned r = (v.u + 0x7FFFu + ((v.u >> 16) & 1u)) >> 16;
    return (unsigned short)r;
}

#define GLOAD_LDS16(gsrc, ldst)                                                        \
    __builtin_amdgcn_global_load_lds(                                                  \
        (const __attribute__((address_space(1))) void*)(gsrc),                         \
        (__attribute__((address_space(3))) void*)(ldst), 16, 0, 0)

// ---------------- prep: analytic y-sort + inverse CSR + amask zero ----------------
// RGC lattice: pos=[i,j], y = sqrt(3)*(i-j)*L (+noise 0.155L, sub-band). So
// key = (i-j)+31 sorts by y WITHOUT reading act (saves a 134MB pass). If this
// model were ever wrong, only sparsity (speed) degrades — correctness comes from
// the measured nzb/amask masks.
__global__ __launch_bounds__(256) void prep_kernel(const int* __restrict__ lgn_idx,
                                                   int* __restrict__ order,
                                                   int* __restrict__ inv_off,
                                                   int* __restrict__ inv_j,
                                                   unsigned int* __restrict__ amask) {
    __shared__ int bins[64];
    __shared__ int cnt[KF];             // 8 KB
    __shared__ int part[256];
    __shared__ int spart[257];
    const int t = threadIdx.x;
    if (t < 64) bins[t] = 0;
    if (t < 16) amask[t] = 0u;
    __syncthreads();
    for (int k = t; k < KF; k += 256) {
        int base = k & 1023;
        int key = ((base >> 5) - (base & 31)) + 31;   // 0..62
        atomicAdd(&bins[key], 1);
    }
    __syncthreads();
    if (t == 0) {
        int run = 0;
        for (int b = 0; b < 63; ++b) { int c = bins[b]; bins[b] = run; run += c; }
    }
    __syncthreads();
    for (int k = t; k < KF; k += 256) {
        int base = k & 1023;
        int key = ((base >> 5) - (base & 31)) + 31;
        int slot = atomicAdd(&bins[key], 1);
        order[slot] = k;
    }
    // ---- inverse CSR of lgn_idx ----
    for (int i = t; i < KF; i += 256) cnt[i] = 0;
    __syncthreads();
    for (int j = t; j < KEXTRA; j += 256) atomicAdd(&cnt[lgn_idx[j]], 1);
    __syncthreads();
    const int base8 = t * 8;
    int local[8];
    {
        int s = 0;
        #pragma unroll
        for (int i = 0; i < 8; ++i) { local[i] = s; s += cnt[base8 + i]; }
        part[t] = s;
    }
    __syncthreads();
    if (t == 0) {
        int run = 0;
        for (int i = 0; i < 256; ++i) { spart[i] = run; run += part[i]; }
        spart[256] = run;
    }
    __syncthreads();
    #pragma unroll
    for (int i = 0; i < 8; ++i) {
        int o = spart[t] + local[i];
        inv_off[base8 + i] = o;
        cnt[base8 + i] = o;             // reuse as scatter cursor
    }
    if (t == 0) inv_off[KF] = spart[256];
    __syncthreads();
    for (int j = t; j < KEXTRA; j += 256) {
        int s = atomicAdd(&cnt[lgn_idx[j]], 1);
        inv_j[s] = j;
    }
}

// ---------------- combo: lgn stage (by<32) || conn fold (by>=32) ----------------
// Both halves depend only on prep, so merging them overlaps fold's 84MB conn read
// with lgn's write-heavy phase instead of serializing the two kernels.
__global__ __launch_bounds__(256) void combo_kernel(const float* __restrict__ x,
                                                    const float* __restrict__ act_on,
                                                    const float* __restrict__ act_off,
                                                    const float* __restrict__ conn,
                                                    const int* __restrict__ lgn_idx,
                                                    const int* __restrict__ order,
                                                    const int* __restrict__ inv_off,
                                                    const int* __restrict__ inv_j,
                                                    float* __restrict__ r,
                                                    float* __restrict__ l,
                                                    unsigned short* __restrict__ rbt,
                                                    unsigned char* __restrict__ nzb,
                                                    unsigned short* __restrict__ Ab,
                                                    unsigned int* __restrict__ amask) {
    __shared__ unsigned short tile[64][66];
    __shared__ float acc[KF];
    __shared__ int nzf;
    __shared__ unsigned int rmask;
    const int t = threadIdx.x;

    if (blockIdx.y < KTILES) {
        // ======== lgn path: r, l (incl. dups via inverse CSR), rbt, nzb ========
        const int k0 = blockIdx.y * 64;     // slot base (sorted)
        const int n0 = blockIdx.x * 64;     // pixel tile base
        if (t == 0) nzf = 0;
        __syncthreads();
        #pragma unroll
        for (int p = 0; p < 4; ++p) {
            int row  = p * 16 + (t >> 4);
            int kk   = k0 + row;            // slot
            int lrow = order[kk];           // original row id (< 2048)
            int c4   = t & 15;
            int px   = n0 + c4 * 4;
            float4 xv = *reinterpret_cast<const float4*>(&x[px]);
            float4 d;
            if (lrow < 1024) {
                float4 a = *reinterpret_cast<const float4*>(&act_on[(size_t)lrow * NPIX + px]);
                d.x = xv.x * a.x; d.y = xv.y * a.y; d.z = xv.z * a.z; d.w = xv.w * a.w;
            } else {
                float4 a = *reinterpret_cast<const float4*>(&act_off[(size_t)(lrow - 1024) * NPIX + px]);
                d.x = (1.f - xv.x) * a.x; d.y = (1.f - xv.y) * a.y;
                d.z = (1.f - xv.z) * a.z; d.w = (1.f - xv.w) * a.w;
            }
            *reinterpret_cast<float4*>(&l[(size_t)lrow * NPIX + px]) = d;
            *reinterpret_cast<float4*>(&r[(size_t)lrow * NPIX + px]) = d;
            int e0 = inv_off[lrow], e1 = inv_off[lrow + 1];
            for (int e = e0; e < e1; ++e)
                *reinterpret_cast<float4*>(&l[(size_t)(NRROWS + inv_j[e]) * NPIX + px]) = d;
            tile[row][c4 * 4 + 0] = f2b(d.x);
            tile[row][c4 * 4 + 1] = f2b(d.y);
            tile[row][c4 * 4 + 2] = f2b(d.z);
            tile[row][c4 * 4 + 3] = f2b(d.w);
            if (d.x != 0.f || d.y != 0.f || d.z != 0.f || d.w != 0.f) nzf = 1; // benign race
        }
        __syncthreads();
        #pragma unroll
        for (int p = 0; p < 4; ++p) {
            int nn = p * 16 + (t >> 4);     // output row (= pixel)
            int k4 = t & 15;
            ushort4 s;
            s.x = tile[k4 * 4 + 0][nn];
            s.y = tile[k4 * 4 + 1][nn];
            s.z = tile[k4 * 4 + 2][nn];
            s.w = tile[k4 * 4 + 3][nn];
            *reinterpret_cast<ushort4*>(&rbt[(size_t)(n0 + nn) * KF + k0 + k4 * 4]) = s;
        }
        if (t == 0) nzb[blockIdx.y * 256 + blockIdx.x] = (unsigned char)nzf;
    } else {
        // ======== fold path: Abf[row][s] = f2b(folded[order[s]]), amask ========
        const int row = (blockIdx.y - KTILES) * 256 + blockIdx.x;   // 0..4095
        if (t == 0) rmask = 0u;
        const float* crow = conn + (size_t)row * GK;
        #pragma unroll
        for (int i = 0; i < KF / 256; ++i)
            acc[t + 256 * i] = crow[t + 256 * i];
        __syncthreads();
        #pragma unroll
        for (int j = 0; j < KEXTRA / 256; ++j) {
            int jj = t + 256 * j;
            float v = crow[KF + jj];
            atomicAdd(&acc[lgn_idx[jj]], v);
        }
        __syncthreads();
        unsigned int local = 0u;
        #pragma unroll
        for (int i = 0; i < KF / 256; ++i) {
            int c = t + 256 * i;
            float v = acc[order[c]];
            Ab[(size_t)row * KF + c] = f2b(v);
            if (fabsf(v) >= TAU) local |= 1u << (c >> 6);
        }
        atomicOr(&rmask, local);
        __syncthreads();
        if (t == 0) atomicOr(&amask[row >> 8], rmask);
    }
}

// ---------------- per-col-block nonzero k-tile bitmask ----------------
__global__ __launch_bounds__(64) void bmask_build_kernel(const unsigned char* __restrict__ nzb,
                                                         unsigned int* __restrict__ bmask) {
    const int c = threadIdx.x;          // col-block 0..63 (256 px each)
    unsigned int m = 0u;
    for (int kt = 0; kt < KTILES; ++kt) {
        const unsigned char* p = nzb + kt * 256 + c * 4;
        if (p[0] | p[1] | p[2] | p[3]) m |= 1u << kt;
    }
    bmask[c] = m;
}

// ---------------- Stage 3: v = conn_folded @ r — doubly block-sparse ----------
// 2-barrier schedule (R4); k-tile list = bmask(nb) & amask(mb). cnt==0 blocks
// write zeros (true v there <= ~5e-5). BK=64 with 128B row stride + XOR swizzle
// is load-bearing (R9 lesson: BK=32's 64B stride -> 8-way bank conflict).
__global__ __launch_bounds__(512, 2) void gemm8_kernel(const unsigned short* __restrict__ Ab, // conn_folded bf16 [4096][2048] (sorted cols)
                                                       const unsigned short* __restrict__ Bb, // rbt [16384][2048] (sorted cols)
                                                       const unsigned int* __restrict__ bmask, // [64]
                                                       const unsigned int* __restrict__ amask, // [16]
                                                       float* __restrict__ C) {               // v [4096][16384]
    __shared__ unsigned short lds[2][2][256][64];   // [buf][A=0/B=1][row][col]
    __shared__ int s_klist[KTILES];
    __shared__ int s_cnt;

    const int tid  = threadIdx.x;
    const int lane = tid & 63;
    const int wid  = tid >> 6;
    const int wm   = wid >> 2;
    const int wn   = wid & 3;

    // XCD-aware bijective swizzle: 1024 wg, 8 XCDs, m-fast within XCD chunk.
    int bid = blockIdx.x;
    int swz = (bid & 7) * 128 + (bid >> 3);
    int mb  = swz & 15;
    int nb  = swz >> 4;
    const int row0 = mb * 256;
    const int col0 = nb * 256;

    if (tid == 0) {
        unsigned int m = bmask[nb] & amask[mb];
        int c = 0;
        while (m) { int kt = __ffs(m) - 1; m &= m - 1u; s_klist[c++] = kt; }
        s_cnt = c;
    }
    __syncthreads();                    // publish s_klist/s_cnt
    const int cnt = s_cnt;

    const int strow = tid >> 3;                 // 0..63
    const int gc    = (lane & 7) ^ (lane >> 3);

#define STAGE_A(buf, rnd, kt)                                                          \
    GLOAD_LDS16(&Ab[(size_t)(row0 + (rnd) * 64 + strow) * KF + (kt) * BK8 + gc * 8],   \
                &lds[buf][0][(rnd) * 64 + strow][(lane & 7) * 8])
#define STAGE_B(buf, rnd, kt)                                                          \
    GLOAD_LDS16(&Bb[(size_t)(col0 + (rnd) * 64 + strow) * KF + (kt) * BK8 + gc * 8],   \
                &lds[buf][1][(rnd) * 64 + strow][(lane & 7) * 8])
#define FRAG(buf, op, row, c)                                                          \
    __builtin_bit_cast(bf16x8, *reinterpret_cast<const ushortx8*>(                     \
        &lds[buf][op][row][(((c) ^ ((row) & 7)) * 8)]))

    f32x4 acc[2][2][4][2] = {};
    const int fr = lane & 15;
    const int kg = lane >> 4;

    bf16x8 af[2][4][2];
    bf16x8 b[2][2];

    if (cnt > 0) {
        const int kt0 = s_klist[0];
        STAGE_A(0, 0, kt0); STAGE_A(0, 1, kt0); STAGE_A(0, 2, kt0); STAGE_A(0, 3, kt0);
        STAGE_B(0, 0, kt0); STAGE_B(0, 1, kt0); STAGE_B(0, 2, kt0); STAGE_B(0, 3, kt0);
        asm volatile("s_waitcnt vmcnt(2)" ::: "memory");   // A(0)+B-lo(0) landed
        __builtin_amdgcn_s_barrier();

        for (int t = 0; t < cnt - 1; ++t) {
            const int cur = t & 1;
            const int nxt = cur ^ 1;
            const int ktn = s_klist[t + 1];

            // ======== ph0: Q(0,0) — consume A-lo, B-lo; stage A(next) ========
            #pragma unroll
            for (int m = 0; m < 4; ++m)
                #pragma unroll
                for (int ks = 0; ks < 2; ++ks)
                    af[0][m][ks] = FRAG(cur, 0, wm * 64 + m * 16 + fr, ks * 4 + kg);
            #pragma unroll
            for (int n = 0; n < 2; ++n)
                #pragma unroll
                for (int ks = 0; ks < 2; ++ks)
                    b[n][ks] = FRAG(cur, 1, wn * 32 + n * 16 + fr, ks * 4 + kg);
            STAGE_A(nxt, 0, ktn); STAGE_A(nxt, 1, ktn);
            STAGE_A(nxt, 2, ktn); STAGE_A(nxt, 3, ktn);
            __builtin_amdgcn_s_setprio(1);
            #pragma unroll
            for (int m = 0; m < 4; ++m)
                #pragma unroll
                for (int n = 0; n < 2; ++n)
                    #pragma unroll
                    for (int ks = 0; ks < 2; ++ks)
                        acc[0][0][m][n] = __builtin_amdgcn_mfma_f32_16x16x32_bf16(af[0][m][ks], b[n][ks], acc[0][0][m][n], 0, 0, 0);
            __builtin_amdgcn_s_setprio(0);

            // ======== ph1: Q(1,0) — consume A-hi; stage B(next) ========
            #pragma unroll
            for (int m = 0; m < 4; ++m)
                #pragma unroll
                for (int ks = 0; ks < 2; ++ks)
                    af[1][m][ks] = FRAG(cur, 0, 128 + wm * 64 + m * 16 + fr, ks * 4 + kg);
            STAGE_B(nxt, 0, ktn); STAGE_B(nxt, 1, ktn);
            STAGE_B(nxt, 2, ktn); STAGE_B(nxt, 3, ktn);
            __builtin_amdgcn_s_setprio(1);
            #pragma unroll
            for (int m = 0; m < 4; ++m)
                #pragma unroll
                for (int n = 0; n < 2; ++n)
                    #pragma unroll
                    for (int ks = 0; ks < 2; ++ks)
                        acc[1][0][m][n] = __builtin_amdgcn_mfma_f32_16x16x32_bf16(af[1][m][ks], b[n][ks], acc[1][0][m][n], 0, 0, 0);
            __builtin_amdgcn_s_setprio(0);
            asm volatile("s_waitcnt vmcnt(8)" ::: "memory");         // B-hi(t) landed
            __builtin_amdgcn_s_barrier();                            // publish B-hi(t)

            // ======== ph2: Q(1,1) — consume B-hi ========
            #pragma unroll
            for (int n = 0; n < 2; ++n)
                #pragma unroll
                for (int ks = 0; ks < 2; ++ks)
                    b[n][ks] = FRAG(cur, 1, 128 + wn * 32 + n * 16 + fr, ks * 4 + kg);
            __builtin_amdgcn_s_setprio(1);
            #pragma unroll
            for (int m = 0; m < 4; ++m)
                #pragma unroll
                for (int n = 0; n < 2; ++n)
                    #pragma unroll
                    for (int ks = 0; ks < 2; ++ks)
                        acc[1][1][m][n] = __builtin_amdgcn_mfma_f32_16x16x32_bf16(af[1][m][ks], b[n][ks], acc[1][1][m][n], 0, 0, 0);
            __builtin_amdgcn_s_setprio(0);

            // ======== ph3: Q(0,1) — pure-reg ========
            __builtin_amdgcn_s_setprio(1);
            #pragma unroll
            for (int m = 0; m < 4; ++m)
                #pragma unroll
                for (int n = 0; n < 2; ++n)
                    #pragma unroll
                    for (int ks = 0; ks < 2; ++ks)
                        acc[0][1][m][n] = __builtin_amdgcn_mfma_f32_16x16x32_bf16(af[0][m][ks], b[n][ks], acc[0][1][m][n], 0, 0, 0);
            __builtin_amdgcn_s_setprio(0);
            asm volatile("s_waitcnt vmcnt(2)" ::: "memory");         // A(next)+B-lo(next) landed
            __builtin_amdgcn_s_barrier();                            // publish next tile inputs
        }

        // ======== epilogue: last k-tile ========
        {
            const int cur = (cnt - 1) & 1;
            #pragma unroll
            for (int m = 0; m < 4; ++m)
                #pragma unroll
                for (int ks = 0; ks < 2; ++ks) {
                    af[0][m][ks] = FRAG(cur, 0, wm * 64 + m * 16 + fr, ks * 4 + kg);
                    af[1][m][ks] = FRAG(cur, 0, 128 + wm * 64 + m * 16 + fr, ks * 4 + kg);
                }
            #pragma unroll
            for (int n = 0; n < 2; ++n)
                #pragma unroll
                for (int ks = 0; ks < 2; ++ks)
                    b[n][ks] = FRAG(cur, 1, wn * 32 + n * 16 + fr, ks * 4 + kg);
            #pragma unroll
            for (int m = 0; m < 4; ++m)
                #pragma unroll
                for (int n = 0; n < 2; ++n)
                    #pragma unroll
                    for (int ks = 0; ks < 2; ++ks) {
                        acc[0][0][m][n] = __builtin_amdgcn_mfma_f32_16x16x32_bf16(af[0][m][ks], b[n][ks], acc[0][0][m][n], 0, 0, 0);
                        acc[1][0][m][n] = __builtin_amdgcn_mfma_f32_16x16x32_bf16(af[1][m][ks], b[n][ks], acc[1][0][m][n], 0, 0, 0);
                    }
            asm volatile("s_waitcnt vmcnt(0)" ::: "memory");         // B-hi(last) landed
            __builtin_amdgcn_s_barrier();
            #pragma unroll
            for (int n = 0; n < 2; ++n)
                #pragma unroll
                for (int ks = 0; ks < 2; ++ks)
                    b[n][ks] = FRAG(cur, 1, 128 + wn * 32 + n * 16 + fr, ks * 4 + kg);
            #pragma unroll
            for (int m = 0; m < 4; ++m)
                #pragma unroll
                for (int n = 0; n < 2; ++n)
                    #pragma unroll
                    for (int ks = 0; ks < 2; ++ks) {
                        acc[1][1][m][n] = __builtin_amdgcn_mfma_f32_16x16x32_bf16(af[1][m][ks], b[n][ks], acc[1][1][m][n], 0, 0, 0);
                        acc[0][1][m][n] = __builtin_amdgcn_mfma_f32_16x16x32_bf16(af[0][m][ks], b[n][ks], acc[0][1][m][n], 0, 0, 0);
                    }
        }
    }

    // C write: C/D layout col=lane&15, row=(lane>>4)*4+j
    #pragma unroll
    for (int qm = 0; qm < 2; ++qm)
        #pragma unroll
        for (int qn = 0; qn < 2; ++qn)
            #pragma unroll
            for (int m = 0; m < 4; ++m)
                #pragma unroll
                for (int n = 0; n < 2; ++n) {
                    int rr = row0 + qm * 128 + wm * 64 + m * 16 + kg * 4;
                    int cc = col0 + qn * 128 + wn * 32 + n * 16 + fr;
                    #pragma unroll
                    for (int j = 0; j < 4; ++j)
                        C[(size_t)(rr + j) * NPIX + cc] = acc[qm][qn][m][n][j];
                }
#undef STAGE_A
#undef STAGE_B
#undef FRAG
}

// ---------------- Fallback path (workspace too small) ----------------
__global__ __launch_bounds__(256) void rgc_kernel(const float* __restrict__ x,
                                                  const float* __restrict__ act_on,
                                                  const float* __restrict__ act_off,
                                                  float* __restrict__ r) {
    unsigned f = blockIdx.x * 256u + threadIdx.x;     // float4 index
    unsigned n  = f >> 12;
    unsigned p4 = f & 4095u;
    float4 xv = reinterpret_cast<const float4*>(x)[p4];
    float4 a, o;
    if (n < 1024u) {
        a = reinterpret_cast<const float4*>(act_on)[(size_t)n * 4096u + p4];
        o.x = xv.x * a.x; o.y = xv.y * a.y; o.z = xv.z * a.z; o.w = xv.w * a.w;
    } else {
        a = reinterpret_cast<const float4*>(act_off)[(size_t)(n - 1024u) * 4096u + p4];
        o.x = (1.f - xv.x) * a.x; o.y = (1.f - xv.y) * a.y;
        o.z = (1.f - xv.z) * a.z; o.w = (1.f - xv.w) * a.w;
    }
    reinterpret_cast<float4*>(r)[f] = o;
}

__global__ __launch_bounds__(256) void lgn_kernel(const float* __restrict__ r,
                                                  const int* __restrict__ lgn_idx,
                                                  float* __restrict__ l) {
    unsigned f = blockIdx.x * 256u + threadIdx.x;
    unsigned k  = f >> 12;
    unsigned p4 = f & 4095u;
    unsigned src = (k < 2048u) ? k : (unsigned)lgn_idx[k - 2048u];
    reinterpret_cast<float4*>(l)[f] =
        reinterpret_cast<const float4*>(r)[(size_t)src * 4096u + p4];
}

__global__ __launch_bounds__(256) void gemm_fallback_kernel(const float* __restrict__ A,
                                                            const float* __restrict__ B,
                                                            float* __restrict__ C) {
    const int tid  = threadIdx.x;
    const int lane = tid & 63;
    const int wid  = tid >> 6;
    const int wr   = wid >> 1;
    const int wc   = wid & 1;
    const int row0 = blockIdx.y * 128;
    const int col0 = blockIdx.x * 128;

    __shared__ unsigned short As[4][128][8];
    __shared__ unsigned short Bs[4][128][8];

    f32x4 acc[4][4] = {};

    for (int k0 = 0; k0 < GK; k0 += 32) {
        #pragma unroll
        for (int i = 0; i < 4; ++i) {
            int f  = tid + 256 * i;
            int rr = f >> 3;
            int c4 = f & 7;
            float4 d = *reinterpret_cast<const float4*>(
                &A[(size_t)(row0 + rr) * GK + k0 + c4 * 4]);
            ushort4 s;
            s.x = f2b(d.x); s.y = f2b(d.y); s.z = f2b(d.z); s.w = f2b(d.w);
            *reinterpret_cast<ushort4*>(&As[c4 >> 1][rr][(c4 & 1) * 4]) = s;
        }
        #pragma unroll
        for (int i = 0; i < 4; ++i) {
            int f  = tid + 256 * i;
            int kk = f >> 5;
            int c4 = f & 31;
            float4 d = *reinterpret_cast<const float4*>(
                &B[(size_t)(k0 + kk) * NPIX + col0 + c4 * 4]);
            int g = kk >> 3, j = kk & 7;
            Bs[g][c4 * 4 + 0][j] = f2b(d.x);
            Bs[g][c4 * 4 + 1][j] = f2b(d.y);
            Bs[g][c4 * 4 + 2][j] = f2b(d.z);
            Bs[g][c4 * 4 + 3][j] = f2b(d.w);
        }
        __syncthreads();

        const int fr = lane & 15;
        const int kg = lane >> 4;
        bf16x8 af[4], bfr[4];
        #pragma unroll
        for (int m = 0; m < 4; ++m)
            af[m] = __builtin_bit_cast(bf16x8,
                *reinterpret_cast<const ushortx8*>(&As[kg][wr * 64 + m * 16 + fr][0]));
        #pragma unroll
        for (int n = 0; n < 4; ++n)
            bfr[n] = __builtin_bit_cast(bf16x8,
                *reinterpret_cast<const ushortx8*>(&Bs[kg][wc * 64 + n * 16 + fr][0]));
        #pragma unroll
        for (int m = 0; m < 4; ++m)
            #pragma unroll
            for (int n = 0; n < 4; ++n)
                acc[m][n] = __builtin_amdgcn_mfma_f32_16x16x32_bf16(af[m], bfr[n], acc[m][n], 0, 0, 0);
        __syncthreads();
    }

    #pragma unroll
    for (int m = 0; m < 4; ++m) {
        #pragma unroll
        for (int n = 0; n < 4; ++n) {
            int rr = row0 + wr * 64 + m * 16 + ((lane >> 4) << 2);
            int cc = col0 + wc * 64 + n * 16 + (lane & 15);
            #pragma unroll
            for (int j = 0; j < 4; ++j)
                C[(size_t)(rr + j) * NPIX + cc] = acc[m][n][j];
        }
    }
}

extern "C" void kernel_launch(void* const* d_in, const int* in_sizes, int n_in,
                              void* d_out, int out_size, void* d_ws, size_t ws_size,
                              hipStream_t stream) {
    const float* x       = (const float*)d_in[0];
    const float* act_on  = (const float*)d_in[1];
    const float* act_off = (const float*)d_in[2];
    const float* conn    = (const float*)d_in[3];
    const int*   lgn_idx = (const int*)d_in[4];

    float* out = (float*)d_out;
    float* r = out;                                    // [2048][16384]
    float* l = out + (size_t)NRROWS * NPIX;            // [5120][16384]
    float* v = out + (size_t)(NRROWS + NLROWS) * NPIX; // [4096][16384]

    const size_t rbt_bytes  = (size_t)NPIX * KF * sizeof(unsigned short);   // 67.1 MB
    const size_t conn_bytes = (size_t)NVROWS * KF * sizeof(unsigned short); // 16.8 MB
    const size_t small_bytes = (KF + (KF + 1) + KEXTRA + NCB + 16 + 64) * sizeof(int)
                             + KTILES * 256;

    if (ws_size >= rbt_bytes + conn_bytes + small_bytes) {
        char* wsp = (char*)d_ws;
        unsigned short* rbt    = (unsigned short*)wsp;                wsp += rbt_bytes;
        unsigned short* connb  = (unsigned short*)wsp;                wsp += conn_bytes;
        int*            order  = (int*)wsp;                           wsp += KF * sizeof(int);
        int*            invoff = (int*)wsp;                           wsp += (KF + 1) * sizeof(int);
        int*            invj   = (int*)wsp;                           wsp += KEXTRA * sizeof(int);
        unsigned char*  nzb    = (unsigned char*)wsp;                 wsp += KTILES * 256;
        unsigned int*   bmask  = (unsigned int*)wsp;                  wsp += NCB * sizeof(int);
        unsigned int*   amask  = (unsigned int*)wsp;

        // analytic y-sort + inverse CSR + amask zero (one tiny kernel, no act read)
        prep_kernel<<<1, 256, 0, stream>>>(lgn_idx, order, invoff, invj, amask);
        // combo: lgn stage (r,l,rbt,nzb) || conn fold (connb, amask) — overlapped
        dim3 tg(NPIX / 64, KTILES + NVROWS / 256);
        combo_kernel<<<tg, 256, 0, stream>>>(x, act_on, act_off, conn, lgn_idx, order,
                                             invoff, invj, r, l, rbt, nzb, connb, amask);
        // per-col-block nonzero k-tile bitmask
        bmask_build_kernel<<<1, 64, 0, stream>>>(nzb, bmask);
        // Stage 3: doubly block-sparse v = conn_folded @ r
        gemm8_kernel<<<(NVROWS / 256) * (NPIX / 256), 512, 0, stream>>>(connb, rbt, bmask, amask, v);
    } else {
        rgc_kernel<<<(NRROWS * (NPIX / 4)) / 256, 256, 0, stream>>>(x, act_on, act_off, r);
        lgn_kernel<<<(NLROWS * (NPIX / 4)) / 256, 256, 0, stream>>>(r, lgn_idx, l);
        dim3 grid(NPIX / 128, NVROWS / 128);
        gemm_fallback_kernel<<<grid, 256, 0, stream>>>(conn, l, v);
    }
}